// Round 1
// 187.307 us; speedup vs baseline: 1.1790x; 1.1790x over previous
//
#include <hip/hip_runtime.h>
#include <hip/hip_bf16.h>

// Round-2 finding: ALL inputs and the output are FP32.
// Round-13: cooperative double-buffered LDS K/V staging in attn.
// Round-14 (this): qkv_gemm was the largest dispatch (56us, MfmaUtil=0) --
// an fp32 VALU GEMM at 36% of the 157TF vector ceiling whose output is
// quantized to bf16 anyway.  Replace qkv_gemm and proj_gemm with bf16 MFMA
// GEMMs (same fragment layout as the verified conv_mfma): W packed to bf16
// in wpack, X packed channel-contiguous bf16 in xpose, attn epilogue emits
// bf16 amt[b][q][256] directly for the projection.

typedef __hip_bfloat16 bf16;
using short8 = __attribute__((ext_vector_type(8))) short;
using short4v = __attribute__((ext_vector_type(4))) short;
using f32x4 = __attribute__((ext_vector_type(4))) float;

__device__ __forceinline__ short f2bs(float f) {
  union { bf16 b; short s; } u; u.b = __float2bfloat16(f); return u.s;
}
__device__ __forceinline__ float bs2f(short s) {
  union { unsigned u; float f; } x; x.u = ((unsigned)(unsigned short)s) << 16;
  return x.f;
}

// ---------------------------------------------------------------------------
// Prepass A: xt[b][34][34][256] bf16 = x NCHW -> spatial-major channel-contig
// with zero halo ring, PLUS dense xb[b][p][256] bf16 (no halo) for the MFMA
// 1x1-conv GEMMs.  grid (8, 34), block 256.
// ---------------------------------------------------------------------------
__global__ __launch_bounds__(256) void xpose(
    const float* __restrict__ X, short* __restrict__ xt,
    short* __restrict__ xb) {
  const int b = blockIdx.x, r = blockIdx.y;   // r in 0..33 (halo coords)
  const int tid = threadIdx.x;
  const bool rin = (r >= 1) && (r <= 32);
  for (int idx = tid; idx < 34 * 256; idx += 256) {
    int cc = idx >> 8, c = idx & 255;
    short s = 0;
    if (rin && cc >= 1 && cc <= 32) {
      s = f2bs(X[((size_t)b * 256 + c) * 1024 + (r - 1) * 32 + (cc - 1)]);
      int p = (r - 1) * 32 + (cc - 1);
      xb[((size_t)b * 1024 + p) * 256 + c] = s;
    }
    xt[(((size_t)b * 34 + r) * 34 + cc) * 256 + c] = s;
  }
}

// ---------------------------------------------------------------------------
// Prepass B: Wb[tap][o][c] bf16 from w_out[o][c][3][3] (blocks 0..2303),
// Wq[o][c] bf16 from w_qkv (blocks 2304..3071),
// Wa[o][c] bf16 from w_attn (blocks 3072..3327).  grid 3328, block 256.
// ---------------------------------------------------------------------------
__global__ __launch_bounds__(256) void wpack(
    const float* __restrict__ Wc, short* __restrict__ Wb,
    const float* __restrict__ wq, short* __restrict__ Wq,
    const float* __restrict__ wa, short* __restrict__ Wa) {
  const int bid = blockIdx.x;
  if (bid < 2304) {
    int idx = bid * 256 + threadIdx.x;     // tap*65536 + o*256 + c
    int tap = idx >> 16;
    int rest = idx & 65535;
    int o = rest >> 8, c = rest & 255;
    Wb[idx] = f2bs(Wc[((size_t)o * 256 + c) * 9 + tap]);
  } else if (bid < 3072) {
    int idx = (bid - 2304) * 256 + threadIdx.x;
    Wq[idx] = f2bs(wq[idx]);
  } else {
    int idx = (bid - 3072) * 256 + threadIdx.x;
    Wa[idx] = f2bs(wa[idx]);
  }
}

// ---------------------------------------------------------------------------
// Kernel 1 (v8): QKV 1x1 conv as bf16 MFMA GEMM.  grid (16, 6, 8), block 256
// = 4 waves.  Wave w: o-tiles {og+w*16, og+w*16+64}, p-tiles {p0+16*pp}.
// K=256 fully unrolled, operands direct from L2 (W 384KB + X 4MB resident).
// Epilogue emits MFMA-ready bf16:
//   qsb[bnh][q][d] (scaled) | ksb[bnh][key][d] | vtb[bnh][d][key]
// ---------------------------------------------------------------------------
__global__ __launch_bounds__(256) void qkv_mfma(
    const short* __restrict__ Wq, const short* __restrict__ xb,
    const float* __restrict__ bias,
    short* __restrict__ qsb, short* __restrict__ ksb, short* __restrict__ vtb) {
  const int tid = threadIdx.x;
  const int w = tid >> 6, lane = tid & 63;
  const int col = lane & 15, grp = lane >> 4, g8 = grp * 8;
  const int b = blockIdx.z;
  const int p0 = blockIdx.x * 64;
  const int og = blockIdx.y * 128;
  const int ob = og + w * 16;

  const short* wa0 = Wq + (size_t)(ob + col) * 256 + g8;
  const short* wa1 = wa0 + (size_t)64 * 256;
  const short* xp0 = xb + ((size_t)b * 1024 + p0 + col) * 256 + g8;
  const short* xp1 = xp0 + (size_t)16 * 256;
  const short* xp2 = xp0 + (size_t)32 * 256;
  const short* xp3 = xp0 + (size_t)48 * 256;

  f32x4 acc[2][4] = {};
#pragma unroll
  for (int c8 = 0; c8 < 8; ++c8) {
    const int chb = c8 * 32;
    short8 a0 = *(const short8*)(wa0 + chb);
    short8 a1 = *(const short8*)(wa1 + chb);
    short8 b0 = *(const short8*)(xp0 + chb);
    short8 b1 = *(const short8*)(xp1 + chb);
    short8 b2 = *(const short8*)(xp2 + chb);
    short8 b3 = *(const short8*)(xp3 + chb);
    acc[0][0] = __builtin_amdgcn_mfma_f32_16x16x32_bf16(a0, b0, acc[0][0], 0, 0, 0);
    acc[0][1] = __builtin_amdgcn_mfma_f32_16x16x32_bf16(a0, b1, acc[0][1], 0, 0, 0);
    acc[0][2] = __builtin_amdgcn_mfma_f32_16x16x32_bf16(a0, b2, acc[0][2], 0, 0, 0);
    acc[0][3] = __builtin_amdgcn_mfma_f32_16x16x32_bf16(a0, b3, acc[0][3], 0, 0, 0);
    acc[1][0] = __builtin_amdgcn_mfma_f32_16x16x32_bf16(a1, b0, acc[1][0], 0, 0, 0);
    acc[1][1] = __builtin_amdgcn_mfma_f32_16x16x32_bf16(a1, b1, acc[1][1], 0, 0, 0);
    acc[1][2] = __builtin_amdgcn_mfma_f32_16x16x32_bf16(a1, b2, acc[1][2], 0, 0, 0);
    acc[1][3] = __builtin_amdgcn_mfma_f32_16x16x32_bf16(a1, b3, acc[1][3], 0, 0, 0);
  }

  const float qscale = 0.17677669529663687f;  // 32^-0.5
#pragma unroll
  for (int j = 0; j < 2; ++j) {
    const int obase = ob + j * 64 + grp * 4;   // + r gives the output chan
    const int sect = obase >> 8;               // 0=q 1=k 2=v (tile-uniform)
    const int nh = (obase >> 5) & 7;
    const int d0 = obase & 31;                 // d0..d0+3 consecutive
    const size_t hb = ((size_t)(b * 8 + nh)) * 1024;
    float bv[4];
#pragma unroll
    for (int r = 0; r < 4; ++r) bv[r] = bias[obase + r];
    if (sect == 0) {
#pragma unroll
      for (int pp = 0; pp < 4; ++pp) {
        const int p = p0 + pp * 16 + col;
        short4v o4;
#pragma unroll
        for (int r = 0; r < 4; ++r)
          o4[r] = f2bs((acc[j][pp][r] + bv[r]) * qscale);
        *(short4v*)&qsb[(hb + p) * 32 + d0] = o4;
      }
    } else if (sect == 1) {
#pragma unroll
      for (int pp = 0; pp < 4; ++pp) {
        const int p = p0 + pp * 16 + col;
        short4v o4;
#pragma unroll
        for (int r = 0; r < 4; ++r)
          o4[r] = f2bs(acc[j][pp][r] + bv[r]);
        *(short4v*)&ksb[(hb + p) * 32 + d0] = o4;
      }
    } else {
#pragma unroll
      for (int pp = 0; pp < 4; ++pp) {
        const int p = p0 + pp * 16 + col;
#pragma unroll
        for (int r = 0; r < 4; ++r)
          vtb[hb * 32 + (size_t)(d0 + r) * 1024 + p] = f2bs(acc[j][pp][r] + bv[r]);
      }
    }
  }
}

// ---------------------------------------------------------------------------
// Kernel 2 (v7): transposed MFMA flash attention + cooperative LDS K/V
// staging.  grid (16, 64), block 256 = 4 waves; 1 wave = 16 q x 1024 keys.
// Per 32-key chunk: wave w stages fragment w (k0/k1/v0/v1, 16B/lane) into
// kvb[slot^1]; all waves read all 4 fragments from kvb[slot] (lane-linear
// b128, conflict-free); one __syncthreads per chunk flips slots.
// Round-14: epilogue writes bf16 amt[b][q][256] (channel-contig) for the
// MFMA projection instead of fp32 am[bnh][d][q].
// ---------------------------------------------------------------------------
__global__ __launch_bounds__(256, 4) void attn_mfma(
    const short* __restrict__ qsb, const short* __restrict__ ksb,
    const short* __restrict__ vtb,
    const float* __restrict__ relw_g, const float* __restrict__ relh_g,
    short* __restrict__ amt) {
  const int tid = threadIdx.x;
  const int w = tid >> 6, lane = tid & 63;
  const int col = lane & 15, grp = lane >> 4, g8 = grp * 8;
  const int qt = blockIdx.x * 4 + w;       // q-tile 0..63
  const int bnh = blockIdx.y;
  const int q0 = qt * 16;
  const int i = qt >> 1;                   // query row, constant per wave
  const int j0 = (qt & 1) * 16;            // query col base

  const short* Qb = qsb + (size_t)bnh * 32768;
  const short* Kb = ksb + (size_t)bnh * 32768;
  const short* Vb = vtb + (size_t)bnh * 32768;

  __shared__ short Gh_s[4][16][68];  // [wave][q][m]  8.5KB
  __shared__ short Gw_s[4][16][68];  // [wave][q][m]  8.5KB
  __shared__ short Pt_s[4][16][40];  // [wave][q][key] 5KB
  __shared__ short kvb[2][4][512];   // [slot][frag][lane*8]  8KB

  // my wave's staging source: fragment w, per-lane 16B gather
  const short* gsrc;
  int gstep;
  if (w == 0)      { gsrc = Kb + (size_t)col * 32 + g8;          gstep = 1024; }
  else if (w == 1) { gsrc = Kb + (size_t)(16 + col) * 32 + g8;   gstep = 1024; }
  else if (w == 2) { gsrc = Vb + (size_t)col * 1024 + g8;        gstep = 32;   }
  else             { gsrc = Vb + (size_t)(16 + col) * 1024 + g8; gstep = 32;   }

  short8 stg = *(const short8*)gsrc;            // chunk 0 (in flight below)

  // Q as B-operand fragment (Q^T[k=d][n=q]); 16B contiguous
  short8 b_q = *(const short8*)(Qb + (q0 + col) * 32 + g8);

  // Build G tables transposed: D[m=16t+grp*4+r][q=col] -> G[q][m] b64 writes
  {
    const float* rels[2] = {relh_g, relw_g};
#pragma unroll
    for (int tb = 0; tb < 2; ++tb) {
      const float* relg = rels[tb];
#pragma unroll
      for (int t = 0; t < 4; ++t) {
        int m = 16 * t + col;
        int mc = m > 62 ? 62 : m;            // m=63 junk, never read
        const float* rp = relg + mc * 32 + g8;
        float4 f0 = *(const float4*)rp;
        float4 f1 = *(const float4*)(rp + 4);
        short8 ar;
        ar[0] = f2bs(f0.x); ar[1] = f2bs(f0.y);
        ar[2] = f2bs(f0.z); ar[3] = f2bs(f0.w);
        ar[4] = f2bs(f1.x); ar[5] = f2bs(f1.y);
        ar[6] = f2bs(f1.z); ar[7] = f2bs(f1.w);
        f32x4 d = __builtin_amdgcn_mfma_f32_16x16x32_bf16(
            ar, b_q, (f32x4){0.f, 0.f, 0.f, 0.f}, 0, 0, 0);
        short4v o;
        o[0] = f2bs(d[0]); o[1] = f2bs(d[1]);
        o[2] = f2bs(d[2]); o[3] = f2bs(d[3]);
        short* Gd = tb ? &Gw_s[w][0][0] : &Gh_s[w][0][0];
        *(short4v*)(Gd + col * 68 + 16 * t + grp * 4) = o;
      }
    }
  }
  __asm__ volatile("s_waitcnt lgkmcnt(0)" ::: "memory");

  // Per-lane Gw values are chunk-independent: y = t*16+grp*4+r, preload 8.
  float gw[8];
#pragma unroll
  for (int t = 0; t < 2; ++t)
#pragma unroll
    for (int r = 0; r < 4; ++r)
      gw[t * 4 + r] =
          bs2f(Gw_s[w][col][t * 16 + grp * 4 + r - j0 - col + 31]);

  const short8 a_one = {0x3F80, 0x3F80, 0x3F80, 0x3F80,
                        0x3F80, 0x3F80, 0x3F80, 0x3F80};

  f32x4 acc0 = {0.f, 0.f, 0.f, 0.f};   // O^T d = grp*4+r,     q = col
  f32x4 acc1 = {0.f, 0.f, 0.f, 0.f};   // O^T d = 16+grp*4+r
  f32x4 accl = {0.f, 0.f, 0.f, 0.f};   // l[q=col] in every reg

  // commit chunk-0 stage, make visible to all waves
  *(short8*)&kvb[0][w][lane * 8] = stg;
  __syncthreads();

#pragma unroll 1
  for (int c = 0; c < 32; ++c) {
    const int cur = c & 1;
    if (c < 31) stg = *(const short8*)(gsrc + (size_t)(c + 1) * gstep);

    short8 ck0 = *(const short8*)&kvb[cur][0][lane * 8];
    short8 ck1 = *(const short8*)&kvb[cur][1][lane * 8];
    short8 cv0 = *(const short8*)&kvb[cur][2][lane * 8];
    short8 cv1 = *(const short8*)&kvb[cur][3][lane * 8];

    // S^T[key][q]: keys c*32 + (t*16+grp*4+r), q = q0+col
    f32x4 s0 = __builtin_amdgcn_mfma_f32_16x16x32_bf16(
        ck0, b_q, (f32x4){0.f, 0.f, 0.f, 0.f}, 0, 0, 0);
    f32x4 s1 = __builtin_amdgcn_mfma_f32_16x16x32_bf16(
        ck1, b_q, (f32x4){0.f, 0.f, 0.f, 0.f}, 0, 0, 0);
    float gh = bs2f(Gh_s[w][col][c - i + 31]);   // broadcast read
    short4v p0, p1;
#pragma unroll
    for (int r = 0; r < 4; ++r) p0[r] = f2bs(__expf(s0[r] + gh + gw[r]));
#pragma unroll
    for (int r = 0; r < 4; ++r) p1[r] = f2bs(__expf(s1[r] + gh + gw[4 + r]));
    *(short4v*)&Pt_s[w][col][grp * 4] = p0;        // keys 0..15 of chunk
    *(short4v*)&Pt_s[w][col][16 + grp * 4] = p1;   // keys 16..31
    __asm__ volatile("s_waitcnt lgkmcnt(0)" ::: "memory");
    short8 a_p = *(const short8*)&Pt_s[w][col][g8];  // P^T B-frag, b128
    acc0 = __builtin_amdgcn_mfma_f32_16x16x32_bf16(cv0, a_p, acc0, 0, 0, 0);
    acc1 = __builtin_amdgcn_mfma_f32_16x16x32_bf16(cv1, a_p, acc1, 0, 0, 0);
    accl = __builtin_amdgcn_mfma_f32_16x16x32_bf16(a_one, a_p, accl, 0, 0, 0);

    if (c < 31) *(short8*)&kvb[cur ^ 1][w][lane * 8] = stg;  // vmcnt wait here
    __syncthreads();   // everyone done reading cur + next slot fully staged
  }

  // epilogue: all-ones A => every accl reg holds l[q=col].
  // Write bf16 amt[b][q][256] with channel = nh*32 + d.
  float rn = 1.0f / accl[0];
  const int bq = bnh >> 3, nh = bnh & 7;
  short* amb = amt + ((size_t)bq * 1024 + q0 + col) * 256 + nh * 32;
  short4v o4a, o4b;
#pragma unroll
  for (int r = 0; r < 4; ++r) {
    o4a[r] = f2bs(acc0[r] * rn);
    o4b[r] = f2bs(acc1[r] * rn);
  }
  *(short4v*)&amb[grp * 4] = o4a;
  *(short4v*)&amb[16 + grp * 4] = o4b;
}

// ---------------------------------------------------------------------------
// Kernel 3 (v2): output projection as bf16 MFMA GEMM, fp32 out channels
// [256,512).  grid (16, 2, 8), block 256; same structure as qkv_mfma.
// ---------------------------------------------------------------------------
__global__ __launch_bounds__(256) void proj_mfma(
    const short* __restrict__ Wa, const short* __restrict__ amt,
    const float* __restrict__ bias, float* __restrict__ out) {
  const int tid = threadIdx.x;
  const int w = tid >> 6, lane = tid & 63;
  const int col = lane & 15, grp = lane >> 4, g8 = grp * 8;
  const int b = blockIdx.z;
  const int p0 = blockIdx.x * 64;
  const int og = blockIdx.y * 128;
  const int ob = og + w * 16;

  const short* wa0 = Wa + (size_t)(ob + col) * 256 + g8;
  const short* wa1 = wa0 + (size_t)64 * 256;
  const short* xp0 = amt + ((size_t)b * 1024 + p0 + col) * 256 + g8;
  const short* xp1 = xp0 + (size_t)16 * 256;
  const short* xp2 = xp0 + (size_t)32 * 256;
  const short* xp3 = xp0 + (size_t)48 * 256;

  f32x4 acc[2][4] = {};
#pragma unroll
  for (int c8 = 0; c8 < 8; ++c8) {
    const int chb = c8 * 32;
    short8 a0 = *(const short8*)(wa0 + chb);
    short8 a1 = *(const short8*)(wa1 + chb);
    short8 b0 = *(const short8*)(xp0 + chb);
    short8 b1 = *(const short8*)(xp1 + chb);
    short8 b2 = *(const short8*)(xp2 + chb);
    short8 b3 = *(const short8*)(xp3 + chb);
    acc[0][0] = __builtin_amdgcn_mfma_f32_16x16x32_bf16(a0, b0, acc[0][0], 0, 0, 0);
    acc[0][1] = __builtin_amdgcn_mfma_f32_16x16x32_bf16(a0, b1, acc[0][1], 0, 0, 0);
    acc[0][2] = __builtin_amdgcn_mfma_f32_16x16x32_bf16(a0, b2, acc[0][2], 0, 0, 0);
    acc[0][3] = __builtin_amdgcn_mfma_f32_16x16x32_bf16(a0, b3, acc[0][3], 0, 0, 0);
    acc[1][0] = __builtin_amdgcn_mfma_f32_16x16x32_bf16(a1, b0, acc[1][0], 0, 0, 0);
    acc[1][1] = __builtin_amdgcn_mfma_f32_16x16x32_bf16(a1, b1, acc[1][1], 0, 0, 0);
    acc[1][2] = __builtin_amdgcn_mfma_f32_16x16x32_bf16(a1, b2, acc[1][2], 0, 0, 0);
    acc[1][3] = __builtin_amdgcn_mfma_f32_16x16x32_bf16(a1, b3, acc[1][3], 0, 0, 0);
  }

#pragma unroll
  for (int j = 0; j < 2; ++j) {
    const int obase = ob + j * 64 + grp * 4;   // + r gives o in [0,256)
    float bv[4];
#pragma unroll
    for (int r = 0; r < 4; ++r) bv[r] = bias[obase + r];
#pragma unroll
    for (int pp = 0; pp < 4; ++pp) {
      const int p = p0 + pp * 16 + col;
#pragma unroll
      for (int r = 0; r < 4; ++r)
        out[((size_t)b * 512 + 256 + obase + r) * 1024 + p] =
            acc[j][pp][r] + bv[r];
    }
  }
}

// ---------------------------------------------------------------------------
// Kernel 4 (v5): LDS-staged MFMA implicit-GEMM 3x3 conv (round 11,
// unchanged).  grid (32, 2, 8), block 256.
// ---------------------------------------------------------------------------
__global__ __launch_bounds__(256) void conv_mfma(
    const short* __restrict__ xt, const short* __restrict__ Wb,
    const float* __restrict__ bias, float* __restrict__ out) {
  const int tid = threadIdx.x;
  const int w = tid >> 6, lane = tid & 63;
  const int col = lane & 15, grp = lane >> 4, g8 = grp * 8;
  const int r0 = blockIdx.x;            // output row 0..31
  const int oh = blockIdx.y;            // o half 0/1
  const int bb = blockIdx.z;

  __shared__ short xs[3][34][264];      // pitch 264: even bank spread

  {
    const short* src = xt + (((size_t)bb * 34 + r0) * 34) * 256;
    for (int g = tid; g < 3264; g += 256) {       // 3*34*32 8-short groups
      int row = g / 1088;                          // 34*32
      int rem = g - row * 1088;
      int cc = rem >> 5, chg = rem & 31;
      short8 v = *(const short8*)(src + (row * 34 + cc) * 256 + chg * 8);
      *(short8*)&xs[row][cc][chg * 8] = v;
    }
  }
  __syncthreads();

  const int ob0 = oh * 128 + w * 16;    // first o-tile
  const int ob1 = ob0 + 64;             // second o-tile
  const short* Wa0 = Wb + (ob0 + col) * 256 + g8;
  const short* Wa1 = Wb + (ob1 + col) * 256 + g8;

  f32x4 acc00 = {0.f, 0.f, 0.f, 0.f};
  f32x4 acc01 = {0.f, 0.f, 0.f, 0.f};
  f32x4 acc10 = {0.f, 0.f, 0.f, 0.f};
  f32x4 acc11 = {0.f, 0.f, 0.f, 0.f};

#pragma unroll 1
  for (int tap = 0; tap < 9; ++tap) {
    const int u = (tap * 11) >> 5, v = tap - 3 * u;   // exact for tap<9
    const short* wa0 = Wa0 + tap * 65536;
    const short* wa1 = Wa1 + tap * 65536;
    const short* xb0 = &xs[u][col + v][g8];
    const short* xb1 = &xs[u][col + 16 + v][g8];
#pragma unroll
    for (int c8 = 0; c8 < 8; ++c8) {
      const int chb = c8 * 32;
      short8 a0 = *(const short8*)(wa0 + chb);
      short8 a1 = *(const short8*)(wa1 + chb);
      short8 b0 = *(const short8*)(xb0 + chb);
      short8 b1 = *(const short8*)(xb1 + chb);
      acc00 = __builtin_amdgcn_mfma_f32_16x16x32_bf16(a0, b0, acc00, 0, 0, 0);
      acc01 = __builtin_amdgcn_mfma_f32_16x16x32_bf16(a0, b1, acc01, 0, 0, 0);
      acc10 = __builtin_amdgcn_mfma_f32_16x16x32_bf16(a1, b0, acc10, 0, 0, 0);
      acc11 = __builtin_amdgcn_mfma_f32_16x16x32_bf16(a1, b1, acc11, 0, 0, 0);
    }
  }

  float* ob = out + (size_t)bb * 512 * 1024 + r0 * 32;
#pragma unroll
  for (int r = 0; r < 4; ++r) {
    int o0 = ob0 + grp * 4 + r;
    int o1 = ob1 + grp * 4 + r;
    float bv0 = bias[o0], bv1 = bias[o1];
    ob[(size_t)o0 * 1024 + col]      = acc00[r] + bv0;
    ob[(size_t)o0 * 1024 + 16 + col] = acc01[r] + bv0;
    ob[(size_t)o1 * 1024 + col]      = acc10[r] + bv1;
    ob[(size_t)o1 * 1024 + 16 + col] = acc11[r] + bv1;
  }
}

// ---------------------------------------------------------------------------
extern "C" void kernel_launch(void* const* d_in, const int* in_sizes, int n_in,
                              void* d_out, int out_size, void* d_ws, size_t ws_size,
                              hipStream_t stream) {
  const float* x      = (const float*)d_in[0];
  const float* w_qkv  = (const float*)d_in[1];
  const float* b_qkv  = (const float*)d_in[2];
  const float* w_attn = (const float*)d_in[3];
  const float* b_attn = (const float*)d_in[4];
  const float* w_out  = (const float*)d_in[5];
  const float* b_out  = (const float*)d_in[6];
  const float* relw   = (const float*)d_in[7];
  const float* relh   = (const float*)d_in[8];
  float* out = (float*)d_out;

  // ws layout (bytes):
  //   qsb bf16 4MB @0 | ksb 4MB @4M | vtb 4MB @8M | amt bf16 4MB @12M
  //   xt bf16 ~4.52MB @16M | xb bf16 4MB @21M
  //   Wq bf16 384KB @25M | Wa bf16 128KB @25.5M | Wb bf16 1.125MB @26M
  // Total ~27.2MB.
  short* qsb = (short*)d_ws;
  short* ksb = qsb + (size_t)2 * 1024 * 1024;
  short* vtb = ksb + (size_t)2 * 1024 * 1024;
  short* amt = (short*)((char*)d_ws + (size_t)12 * 1024 * 1024);
  short* xt  = (short*)((char*)d_ws + (size_t)16 * 1024 * 1024);
  short* xb  = (short*)((char*)d_ws + (size_t)21 * 1024 * 1024);
  short* Wq  = (short*)((char*)d_ws + (size_t)25 * 1024 * 1024);
  short* Wa  = (short*)((char*)d_ws + (size_t)25 * 1024 * 1024 + 512 * 1024);
  short* Wb  = (short*)((char*)d_ws + (size_t)26 * 1024 * 1024);

  xpose<<<dim3(8, 34), 256, 0, stream>>>(x, xt, xb);
  wpack<<<3328, 256, 0, stream>>>(w_out, Wb, w_qkv, Wq, w_attn, Wa);
  qkv_mfma<<<dim3(16, 6, 8), 256, 0, stream>>>(Wq, xb, b_qkv, qsb, ksb, vtb);
  attn_mfma<<<dim3(16, 64), 256, 0, stream>>>(qsb, ksb, vtb, relw, relh, amt);
  proj_mfma<<<dim3(16, 2, 8), 256, 0, stream>>>(Wa, amt, b_attn, out);
  conv_mfma<<<dim3(32, 2, 8), 256, 0, stream>>>(xt, Wb, b_out, out);
}

// Round 3
// 170.299 us; speedup vs baseline: 1.2967x; 1.0999x over previous
//
#include <hip/hip_runtime.h>
#include <hip/hip_bf16.h>

// Round-2 finding: ALL inputs and the output are FP32.
// Round-13: cooperative double-buffered LDS K/V staging in attn.
// Round-14: qkv/proj converted to bf16 MFMA GEMMs (-33us).
// Round-15: coalesced xpose/wpack via LDS transpose; xb2 fragment-tiled so
//   qkv B-loads are lane-linear.  CRASHED: stage loop ran 32 iters (c up to
//   1023, OOB read on X for b=7).
// Round-16 (this): fix the trip count to 8 (256 ch x 8 float4 / 256 thr).

typedef __hip_bfloat16 bf16;
using short8 = __attribute__((ext_vector_type(8))) short;
using short4v = __attribute__((ext_vector_type(4))) short;
using f32x4 = __attribute__((ext_vector_type(4))) float;

__device__ __forceinline__ short f2bs(float f) {
  union { bf16 b; short s; } u; u.b = __float2bfloat16(f); return u.s;
}
__device__ __forceinline__ float bs2f(short s) {
  union { unsigned u; float f; } x; x.u = ((unsigned)(unsigned short)s) << 16;
  return x.f;
}

// ---------------------------------------------------------------------------
// Prepass A (v4): LDS-transpose repack.
//   xt[b][34][34][256] bf16: spatial-major channel-contig with zero halo.
//   xb2[b][pb][c8][grp][pcol][8] bf16: MFMA-fragment-tiled (pb = p>>4,
//   ch = c8*32+grp*8+j, pcol = p&15) so qkv loads are lane-linear.
// grid (8, 34), block 256.  One block = one spatial row (32 positions).
// ---------------------------------------------------------------------------
__global__ __launch_bounds__(256) void xpose(
    const float* __restrict__ X, short* __restrict__ xt,
    short* __restrict__ xb2) {
  const int b = blockIdx.x, r = blockIdx.y;   // r in 0..33 (halo coords)
  const int tid = threadIdx.x;
  if (r == 0 || r == 33) {                    // full zero halo row
    short8 z = {};
    short* dst = xt + (((size_t)b * 34 + r) * 34) * 256;
    for (int g = tid; g < 1088; g += 256) *(short8*)(dst + g * 8) = z;
    return;
  }
  __shared__ short xls[32][264];              // [p][c], pitch 264
  {
    // coalesced: 8 lanes cover one channel's 32-float row (128B segment);
    // 2048 float4 items / 256 threads = 8 iterations.
    const float* src = X + (size_t)b * 256 * 1024 + (r - 1) * 32;
    for (int it = 0; it < 8; ++it) {
      int idx = it * 256 + tid;
      int c = idx >> 3, pq = idx & 7;
      float4 f4 = *(const float4*)(src + (size_t)c * 1024 + pq * 4);
      xls[pq * 4 + 0][c] = f2bs(f4.x);
      xls[pq * 4 + 1][c] = f2bs(f4.y);
      xls[pq * 4 + 2][c] = f2bs(f4.z);
      xls[pq * 4 + 3][c] = f2bs(f4.w);
    }
  }
  __syncthreads();
  {
    // xt: interior cc=1..32 channel-contig, plus zero halo cols cc=0,33
    short* dst = xt + (((size_t)b * 34 + r) * 34) * 256;
    for (int it = 0; it < 4; ++it) {
      int idx = it * 256 + tid;
      int cc = idx >> 5, co = idx & 31;
      short8 v = *(const short8*)&xls[cc][co * 8];
      *(short8*)(dst + (cc + 1) * 256 + co * 8) = v;
    }
    if (tid < 64) {
      short8 z = {};
      int cce = (tid >> 5) * 33, co = tid & 31;
      *(short8*)(dst + cce * 256 + co * 8) = z;
    }
  }
  {
    // xb2 fragment-tiled write, lane-contiguous
    short* dst = xb2 + (((size_t)b * 64 + (r - 1) * 2) * 8) * 512;
    for (int it = 0; it < 4; ++it) {
      int g = it * 256 + tid;
      int half = g >> 9, c8 = (g >> 6) & 7, grp = (g >> 4) & 3, pcol = g & 15;
      short8 v = *(const short8*)&xls[half * 16 + pcol][c8 * 32 + grp * 8];
      *(short8*)(dst + ((half * 8 + c8) * 64 + grp * 16 + pcol) * 8) = v;
    }
  }
}

// ---------------------------------------------------------------------------
// Prepass B (v2): coalesced weight packs.
//   blocks [0,256):   conv o-channel transpose via LDS -> Wb[tap][o][c]
//   blocks [256,1024): Wq straight copy
//   blocks [1024,1280): Wa straight copy
// grid 1280, block 256.
// ---------------------------------------------------------------------------
__global__ __launch_bounds__(256) void wpack(
    const float* __restrict__ Wc, short* __restrict__ Wb,
    const float* __restrict__ wq, short* __restrict__ Wq,
    const float* __restrict__ wa, short* __restrict__ Wa) {
  const int bid = blockIdx.x;
  const int tid = threadIdx.x;
  if (bid < 256) {
    __shared__ float ws[2304];                 // one o's [c][tap] block
    const float* src = Wc + (size_t)bid * 2304;
    for (int it = 0; it < 9; ++it) ws[it * 256 + tid] = src[it * 256 + tid];
    __syncthreads();
#pragma unroll
    for (int tap = 0; tap < 9; ++tap)          // bank-free: 9 coprime 32
      Wb[tap * 65536 + bid * 256 + tid] = f2bs(ws[tid * 9 + tap]);
  } else if (bid < 1024) {
    int idx = (bid - 256) * 256 + tid;
    Wq[idx] = f2bs(wq[idx]);
  } else {
    int idx = (bid - 1024) * 256 + tid;
    Wa[idx] = f2bs(wa[idx]);
  }
}

// ---------------------------------------------------------------------------
// Kernel 1 (v9): QKV 1x1 conv as bf16 MFMA GEMM.  grid (16, 6, 8), block 256
// = 4 waves.  B-operand fragments read lane-linear from fragment-tiled
// xb2: fragment (pp,c8) at xpb + (pp*8+c8)*512 + lane*8 (coalesced 1KB).
// Epilogue emits MFMA-ready bf16:
//   qsb[bnh][q][d] (scaled) | ksb[bnh][key][d] | vtb[bnh][d][key]
// ---------------------------------------------------------------------------
__global__ __launch_bounds__(256) void qkv_mfma(
    const short* __restrict__ Wq, const short* __restrict__ xb2,
    const float* __restrict__ bias,
    short* __restrict__ qsb, short* __restrict__ ksb, short* __restrict__ vtb) {
  const int tid = threadIdx.x;
  const int w = tid >> 6, lane = tid & 63;
  const int col = lane & 15, grp = lane >> 4, g8 = grp * 8;
  const int b = blockIdx.z;
  const int p0 = blockIdx.x * 64;
  const int og = blockIdx.y * 128;
  const int ob = og + w * 16;

  const short* wa0 = Wq + (size_t)(ob + col) * 256 + g8;
  const short* wa1 = wa0 + (size_t)64 * 256;
  const short* xpb = xb2 + (((size_t)b * 64 + blockIdx.x * 4) * 8) * 512 + lane * 8;

  f32x4 acc[2][4] = {};
#pragma unroll
  for (int c8 = 0; c8 < 8; ++c8) {
    const int chb = c8 * 32;
    short8 a0 = *(const short8*)(wa0 + chb);
    short8 a1 = *(const short8*)(wa1 + chb);
    short8 b0 = *(const short8*)(xpb + c8 * 512);
    short8 b1 = *(const short8*)(xpb + 4096 + c8 * 512);
    short8 b2 = *(const short8*)(xpb + 8192 + c8 * 512);
    short8 b3 = *(const short8*)(xpb + 12288 + c8 * 512);
    acc[0][0] = __builtin_amdgcn_mfma_f32_16x16x32_bf16(a0, b0, acc[0][0], 0, 0, 0);
    acc[0][1] = __builtin_amdgcn_mfma_f32_16x16x32_bf16(a0, b1, acc[0][1], 0, 0, 0);
    acc[0][2] = __builtin_amdgcn_mfma_f32_16x16x32_bf16(a0, b2, acc[0][2], 0, 0, 0);
    acc[0][3] = __builtin_amdgcn_mfma_f32_16x16x32_bf16(a0, b3, acc[0][3], 0, 0, 0);
    acc[1][0] = __builtin_amdgcn_mfma_f32_16x16x32_bf16(a1, b0, acc[1][0], 0, 0, 0);
    acc[1][1] = __builtin_amdgcn_mfma_f32_16x16x32_bf16(a1, b1, acc[1][1], 0, 0, 0);
    acc[1][2] = __builtin_amdgcn_mfma_f32_16x16x32_bf16(a1, b2, acc[1][2], 0, 0, 0);
    acc[1][3] = __builtin_amdgcn_mfma_f32_16x16x32_bf16(a1, b3, acc[1][3], 0, 0, 0);
  }

  const float qscale = 0.17677669529663687f;  // 32^-0.5
#pragma unroll
  for (int j = 0; j < 2; ++j) {
    const int obase = ob + j * 64 + grp * 4;   // + r gives the output chan
    const int sect = obase >> 8;               // 0=q 1=k 2=v (tile-uniform)
    const int nh = (obase >> 5) & 7;
    const int d0 = obase & 31;                 // d0..d0+3 consecutive
    const size_t hb = ((size_t)(b * 8 + nh)) * 1024;
    float bv[4];
#pragma unroll
    for (int r = 0; r < 4; ++r) bv[r] = bias[obase + r];
    if (sect == 0) {
#pragma unroll
      for (int pp = 0; pp < 4; ++pp) {
        const int p = p0 + pp * 16 + col;
        short4v o4;
#pragma unroll
        for (int r = 0; r < 4; ++r)
          o4[r] = f2bs((acc[j][pp][r] + bv[r]) * qscale);
        *(short4v*)&qsb[(hb + p) * 32 + d0] = o4;
      }
    } else if (sect == 1) {
#pragma unroll
      for (int pp = 0; pp < 4; ++pp) {
        const int p = p0 + pp * 16 + col;
        short4v o4;
#pragma unroll
        for (int r = 0; r < 4; ++r)
          o4[r] = f2bs(acc[j][pp][r] + bv[r]);
        *(short4v*)&ksb[(hb + p) * 32 + d0] = o4;
      }
    } else {
#pragma unroll
      for (int pp = 0; pp < 4; ++pp) {
        const int p = p0 + pp * 16 + col;
#pragma unroll
        for (int r = 0; r < 4; ++r)
          vtb[hb * 32 + (size_t)(d0 + r) * 1024 + p] = f2bs(acc[j][pp][r] + bv[r]);
      }
    }
  }
}

// ---------------------------------------------------------------------------
// Kernel 2 (v7): transposed MFMA flash attention + cooperative LDS K/V
// staging (unchanged this round).  grid (16, 64), block 256 = 4 waves.
// ---------------------------------------------------------------------------
__global__ __launch_bounds__(256, 4) void attn_mfma(
    const short* __restrict__ qsb, const short* __restrict__ ksb,
    const short* __restrict__ vtb,
    const float* __restrict__ relw_g, const float* __restrict__ relh_g,
    short* __restrict__ amt) {
  const int tid = threadIdx.x;
  const int w = tid >> 6, lane = tid & 63;
  const int col = lane & 15, grp = lane >> 4, g8 = grp * 8;
  const int qt = blockIdx.x * 4 + w;       // q-tile 0..63
  const int bnh = blockIdx.y;
  const int q0 = qt * 16;
  const int i = qt >> 1;                   // query row, constant per wave
  const int j0 = (qt & 1) * 16;            // query col base

  const short* Qb = qsb + (size_t)bnh * 32768;
  const short* Kb = ksb + (size_t)bnh * 32768;
  const short* Vb = vtb + (size_t)bnh * 32768;

  __shared__ short Gh_s[4][16][68];  // [wave][q][m]  8.5KB
  __shared__ short Gw_s[4][16][68];  // [wave][q][m]  8.5KB
  __shared__ short Pt_s[4][16][40];  // [wave][q][key] 5KB
  __shared__ short kvb[2][4][512];   // [slot][frag][lane*8]  8KB

  // my wave's staging source: fragment w, per-lane 16B gather
  const short* gsrc;
  int gstep;
  if (w == 0)      { gsrc = Kb + (size_t)col * 32 + g8;          gstep = 1024; }
  else if (w == 1) { gsrc = Kb + (size_t)(16 + col) * 32 + g8;   gstep = 1024; }
  else if (w == 2) { gsrc = Vb + (size_t)col * 1024 + g8;        gstep = 32;   }
  else             { gsrc = Vb + (size_t)(16 + col) * 1024 + g8; gstep = 32;   }

  short8 stg = *(const short8*)gsrc;            // chunk 0 (in flight below)

  // Q as B-operand fragment (Q^T[k=d][n=q]); 16B contiguous
  short8 b_q = *(const short8*)(Qb + (q0 + col) * 32 + g8);

  // Build G tables transposed: D[m=16t+grp*4+r][q=col] -> G[q][m] b64 writes
  {
    const float* rels[2] = {relh_g, relw_g};
#pragma unroll
    for (int tb = 0; tb < 2; ++tb) {
      const float* relg = rels[tb];
#pragma unroll
      for (int t = 0; t < 4; ++t) {
        int m = 16 * t + col;
        int mc = m > 62 ? 62 : m;            // m=63 junk, never read
        const float* rp = relg + mc * 32 + g8;
        float4 f0 = *(const float4*)rp;
        float4 f1 = *(const float4*)(rp + 4);
        short8 ar;
        ar[0] = f2bs(f0.x); ar[1] = f2bs(f0.y);
        ar[2] = f2bs(f0.z); ar[3] = f2bs(f0.w);
        ar[4] = f2bs(f1.x); ar[5] = f2bs(f1.y);
        ar[6] = f2bs(f1.z); ar[7] = f2bs(f1.w);
        f32x4 d = __builtin_amdgcn_mfma_f32_16x16x32_bf16(
            ar, b_q, (f32x4){0.f, 0.f, 0.f, 0.f}, 0, 0, 0);
        short4v o;
        o[0] = f2bs(d[0]); o[1] = f2bs(d[1]);
        o[2] = f2bs(d[2]); o[3] = f2bs(d[3]);
        short* Gd = tb ? &Gw_s[w][0][0] : &Gh_s[w][0][0];
        *(short4v*)(Gd + col * 68 + 16 * t + grp * 4) = o;
      }
    }
  }
  __asm__ volatile("s_waitcnt lgkmcnt(0)" ::: "memory");

  // Per-lane Gw values are chunk-independent: y = t*16+grp*4+r, preload 8.
  float gw[8];
#pragma unroll
  for (int t = 0; t < 2; ++t)
#pragma unroll
    for (int r = 0; r < 4; ++r)
      gw[t * 4 + r] =
          bs2f(Gw_s[w][col][t * 16 + grp * 4 + r - j0 - col + 31]);

  const short8 a_one = {0x3F80, 0x3F80, 0x3F80, 0x3F80,
                        0x3F80, 0x3F80, 0x3F80, 0x3F80};

  f32x4 acc0 = {0.f, 0.f, 0.f, 0.f};   // O^T d = grp*4+r,     q = col
  f32x4 acc1 = {0.f, 0.f, 0.f, 0.f};   // O^T d = 16+grp*4+r
  f32x4 accl = {0.f, 0.f, 0.f, 0.f};   // l[q=col] in every reg

  // commit chunk-0 stage, make visible to all waves
  *(short8*)&kvb[0][w][lane * 8] = stg;
  __syncthreads();

#pragma unroll 1
  for (int c = 0; c < 32; ++c) {
    const int cur = c & 1;
    if (c < 31) stg = *(const short8*)(gsrc + (size_t)(c + 1) * gstep);

    short8 ck0 = *(const short8*)&kvb[cur][0][lane * 8];
    short8 ck1 = *(const short8*)&kvb[cur][1][lane * 8];
    short8 cv0 = *(const short8*)&kvb[cur][2][lane * 8];
    short8 cv1 = *(const short8*)&kvb[cur][3][lane * 8];

    // S^T[key][q]: keys c*32 + (t*16+grp*4+r), q = q0+col
    f32x4 s0 = __builtin_amdgcn_mfma_f32_16x16x32_bf16(
        ck0, b_q, (f32x4){0.f, 0.f, 0.f, 0.f}, 0, 0, 0);
    f32x4 s1 = __builtin_amdgcn_mfma_f32_16x16x32_bf16(
        ck1, b_q, (f32x4){0.f, 0.f, 0.f, 0.f}, 0, 0, 0);
    float gh = bs2f(Gh_s[w][col][c - i + 31]);   // broadcast read
    short4v p0, p1;
#pragma unroll
    for (int r = 0; r < 4; ++r) p0[r] = f2bs(__expf(s0[r] + gh + gw[r]));
#pragma unroll
    for (int r = 0; r < 4; ++r) p1[r] = f2bs(__expf(s1[r] + gh + gw[4 + r]));
    *(short4v*)&Pt_s[w][col][grp * 4] = p0;        // keys 0..15 of chunk
    *(short4v*)&Pt_s[w][col][16 + grp * 4] = p1;   // keys 16..31
    __asm__ volatile("s_waitcnt lgkmcnt(0)" ::: "memory");
    short8 a_p = *(const short8*)&Pt_s[w][col][g8];  // P^T B-frag, b128
    acc0 = __builtin_amdgcn_mfma_f32_16x16x32_bf16(cv0, a_p, acc0, 0, 0, 0);
    acc1 = __builtin_amdgcn_mfma_f32_16x16x32_bf16(cv1, a_p, acc1, 0, 0, 0);
    accl = __builtin_amdgcn_mfma_f32_16x16x32_bf16(a_one, a_p, accl, 0, 0, 0);

    if (c < 31) *(short8*)&kvb[cur ^ 1][w][lane * 8] = stg;  // vmcnt wait here
    __syncthreads();   // everyone done reading cur + next slot fully staged
  }

  // epilogue: all-ones A => every accl reg holds l[q=col].
  // Write bf16 amt[b][q][256] with channel = nh*32 + d.
  float rn = 1.0f / accl[0];
  const int bq = bnh >> 3, nh = bnh & 7;
  short* amb = amt + ((size_t)bq * 1024 + q0 + col) * 256 + nh * 32;
  short4v o4a, o4b;
#pragma unroll
  for (int r = 0; r < 4; ++r) {
    o4a[r] = f2bs(acc0[r] * rn);
    o4b[r] = f2bs(acc1[r] * rn);
  }
  *(short4v*)&amb[grp * 4] = o4a;
  *(short4v*)&amb[16 + grp * 4] = o4b;
}

// ---------------------------------------------------------------------------
// Kernel 3 (v2): output projection as bf16 MFMA GEMM, fp32 out channels
// [256,512).  grid (16, 2, 8), block 256 (unchanged this round).
// ---------------------------------------------------------------------------
__global__ __launch_bounds__(256) void proj_mfma(
    const short* __restrict__ Wa, const short* __restrict__ amt,
    const float* __restrict__ bias, float* __restrict__ out) {
  const int tid = threadIdx.x;
  const int w = tid >> 6, lane = tid & 63;
  const int col = lane & 15, grp = lane >> 4, g8 = grp * 8;
  const int b = blockIdx.z;
  const int p0 = blockIdx.x * 64;
  const int og = blockIdx.y * 128;
  const int ob = og + w * 16;

  const short* wa0 = Wa + (size_t)(ob + col) * 256 + g8;
  const short* wa1 = wa0 + (size_t)64 * 256;
  const short* xp0 = amt + ((size_t)b * 1024 + p0 + col) * 256 + g8;
  const short* xp1 = xp0 + (size_t)16 * 256;
  const short* xp2 = xp0 + (size_t)32 * 256;
  const short* xp3 = xp0 + (size_t)48 * 256;

  f32x4 acc[2][4] = {};
#pragma unroll
  for (int c8 = 0; c8 < 8; ++c8) {
    const int chb = c8 * 32;
    short8 a0 = *(const short8*)(wa0 + chb);
    short8 a1 = *(const short8*)(wa1 + chb);
    short8 b0 = *(const short8*)(xp0 + chb);
    short8 b1 = *(const short8*)(xp1 + chb);
    short8 b2 = *(const short8*)(xp2 + chb);
    short8 b3 = *(const short8*)(xp3 + chb);
    acc[0][0] = __builtin_amdgcn_mfma_f32_16x16x32_bf16(a0, b0, acc[0][0], 0, 0, 0);
    acc[0][1] = __builtin_amdgcn_mfma_f32_16x16x32_bf16(a0, b1, acc[0][1], 0, 0, 0);
    acc[0][2] = __builtin_amdgcn_mfma_f32_16x16x32_bf16(a0, b2, acc[0][2], 0, 0, 0);
    acc[0][3] = __builtin_amdgcn_mfma_f32_16x16x32_bf16(a0, b3, acc[0][3], 0, 0, 0);
    acc[1][0] = __builtin_amdgcn_mfma_f32_16x16x32_bf16(a1, b0, acc[1][0], 0, 0, 0);
    acc[1][1] = __builtin_amdgcn_mfma_f32_16x16x32_bf16(a1, b1, acc[1][1], 0, 0, 0);
    acc[1][2] = __builtin_amdgcn_mfma_f32_16x16x32_bf16(a1, b2, acc[1][2], 0, 0, 0);
    acc[1][3] = __builtin_amdgcn_mfma_f32_16x16x32_bf16(a1, b3, acc[1][3], 0, 0, 0);
  }

#pragma unroll
  for (int j = 0; j < 2; ++j) {
    const int obase = ob + j * 64 + grp * 4;   // + r gives o in [0,256)
    float bv[4];
#pragma unroll
    for (int r = 0; r < 4; ++r) bv[r] = bias[obase + r];
#pragma unroll
    for (int pp = 0; pp < 4; ++pp) {
      const int p = p0 + pp * 16 + col;
#pragma unroll
      for (int r = 0; r < 4; ++r)
        out[((size_t)b * 512 + 256 + obase + r) * 1024 + p] =
            acc[j][pp][r] + bv[r];
    }
  }
}

// ---------------------------------------------------------------------------
// Kernel 4 (v5): LDS-staged MFMA implicit-GEMM 3x3 conv (unchanged).
// grid (32, 2, 8), block 256.
// ---------------------------------------------------------------------------
__global__ __launch_bounds__(256) void conv_mfma(
    const short* __restrict__ xt, const short* __restrict__ Wb,
    const float* __restrict__ bias, float* __restrict__ out) {
  const int tid = threadIdx.x;
  const int w = tid >> 6, lane = tid & 63;
  const int col = lane & 15, grp = lane >> 4, g8 = grp * 8;
  const int r0 = blockIdx.x;            // output row 0..31
  const int oh = blockIdx.y;            // o half 0/1
  const int bb = blockIdx.z;

  __shared__ short xs[3][34][264];      // pitch 264: even bank spread

  {
    const short* src = xt + (((size_t)bb * 34 + r0) * 34) * 256;
    for (int g = tid; g < 3264; g += 256) {       // 3*34*32 8-short groups
      int row = g / 1088;                          // 34*32
      int rem = g - row * 1088;
      int cc = rem >> 5, chg = rem & 31;
      short8 v = *(const short8*)(src + (row * 34 + cc) * 256 + chg * 8);
      *(short8*)&xs[row][cc][chg * 8] = v;
    }
  }
  __syncthreads();

  const int ob0 = oh * 128 + w * 16;    // first o-tile
  const int ob1 = ob0 + 64;             // second o-tile
  const short* Wa0 = Wb + (ob0 + col) * 256 + g8;
  const short* Wa1 = Wb + (ob1 + col) * 256 + g8;

  f32x4 acc00 = {0.f, 0.f, 0.f, 0.f};
  f32x4 acc01 = {0.f, 0.f, 0.f, 0.f};
  f32x4 acc10 = {0.f, 0.f, 0.f, 0.f};
  f32x4 acc11 = {0.f, 0.f, 0.f, 0.f};

#pragma unroll 1
  for (int tap = 0; tap < 9; ++tap) {
    const int u = (tap * 11) >> 5, v = tap - 3 * u;   // exact for tap<9
    const short* wa0 = Wa0 + tap * 65536;
    const short* wa1 = Wa1 + tap * 65536;
    const short* xb0 = &xs[u][col + v][g8];
    const short* xb1 = &xs[u][col + 16 + v][g8];
#pragma unroll
    for (int c8 = 0; c8 < 8; ++c8) {
      const int chb = c8 * 32;
      short8 a0 = *(const short8*)(wa0 + chb);
      short8 a1 = *(const short8*)(wa1 + chb);
      short8 b0 = *(const short8*)(xb0 + chb);
      short8 b1 = *(const short8*)(xb1 + chb);
      acc00 = __builtin_amdgcn_mfma_f32_16x16x32_bf16(a0, b0, acc00, 0, 0, 0);
      acc01 = __builtin_amdgcn_mfma_f32_16x16x32_bf16(a0, b1, acc01, 0, 0, 0);
      acc10 = __builtin_amdgcn_mfma_f32_16x16x32_bf16(a1, b0, acc10, 0, 0, 0);
      acc11 = __builtin_amdgcn_mfma_f32_16x16x32_bf16(a1, b1, acc11, 0, 0, 0);
    }
  }

  float* ob = out + (size_t)bb * 512 * 1024 + r0 * 32;
#pragma unroll
  for (int r = 0; r < 4; ++r) {
    int o0 = ob0 + grp * 4 + r;
    int o1 = ob1 + grp * 4 + r;
    float bv0 = bias[o0], bv1 = bias[o1];
    ob[(size_t)o0 * 1024 + col]      = acc00[r] + bv0;
    ob[(size_t)o0 * 1024 + 16 + col] = acc01[r] + bv0;
    ob[(size_t)o1 * 1024 + col]      = acc10[r] + bv1;
    ob[(size_t)o1 * 1024 + 16 + col] = acc11[r] + bv1;
  }
}

// ---------------------------------------------------------------------------
extern "C" void kernel_launch(void* const* d_in, const int* in_sizes, int n_in,
                              void* d_out, int out_size, void* d_ws, size_t ws_size,
                              hipStream_t stream) {
  const float* x      = (const float*)d_in[0];
  const float* w_qkv  = (const float*)d_in[1];
  const float* b_qkv  = (const float*)d_in[2];
  const float* w_attn = (const float*)d_in[3];
  const float* b_attn = (const float*)d_in[4];
  const float* w_out  = (const float*)d_in[5];
  const float* b_out  = (const float*)d_in[6];
  const float* relw   = (const float*)d_in[7];
  const float* relh   = (const float*)d_in[8];
  float* out = (float*)d_out;

  // ws layout (bytes):
  //   qsb bf16 4MB @0 | ksb 4MB @4M | vtb 4MB @8M | amt bf16 4MB @12M
  //   xt bf16 ~4.52MB @16M | xb2 bf16 4MB @21M
  //   Wq bf16 384KB @25M | Wa bf16 128KB @25.5M | Wb bf16 1.125MB @26M
  // Total ~27.2MB.
  short* qsb = (short*)d_ws;
  short* ksb = qsb + (size_t)2 * 1024 * 1024;
  short* vtb = ksb + (size_t)2 * 1024 * 1024;
  short* amt = (short*)((char*)d_ws + (size_t)12 * 1024 * 1024);
  short* xt  = (short*)((char*)d_ws + (size_t)16 * 1024 * 1024);
  short* xb2 = (short*)((char*)d_ws + (size_t)21 * 1024 * 1024);
  short* Wq  = (short*)((char*)d_ws + (size_t)25 * 1024 * 1024);
  short* Wa  = (short*)((char*)d_ws + (size_t)25 * 1024 * 1024 + 512 * 1024);
  short* Wb  = (short*)((char*)d_ws + (size_t)26 * 1024 * 1024);

  xpose<<<dim3(8, 34), 256, 0, stream>>>(x, xt, xb2);
  wpack<<<1280, 256, 0, stream>>>(w_out, Wb, w_qkv, Wq, w_attn, Wa);
  qkv_mfma<<<dim3(16, 6, 8), 256, 0, stream>>>(Wq, xb2, b_qkv, qsb, ksb, vtb);
  attn_mfma<<<dim3(16, 64), 256, 0, stream>>>(qsb, ksb, vtb, relw, relh, amt);
  proj_mfma<<<dim3(16, 2, 8), 256, 0, stream>>>(Wa, amt, b_attn, out);
  conv_mfma<<<dim3(32, 2, 8), 256, 0, stream>>>(xt, Wb, b_out, out);
}